// Round 2
// baseline (369.329 us; speedup 1.0000x reference)
//
#include <hip/hip_runtime.h>

// GatedMoE on MI355X (gfx950), fp16 MFMA path, round 6.
// r5 resubmit, hardened: gemm1 token ids in registers (LDS exactly 128KB,
// no pre-loop __syncthreads), explicit vmcnt(0)+sched_barrier before the
// prologue staging so the counted-vmcnt pipeline starts from a clean
// counter. Both GEMMs: counted-vmcnt double-buffered pipeline (T3/T4/T5):
// raw s_barrier, vmcnt(8)/vmcnt(6) never draining in the main loop, stage
// of tile t+2 issued right after the buffer's last-read barrier, s_setprio
// around MFMA clusters. gemm1: 256 tok x 256 vcol tile, 8 waves, SwiGLU
// fused via interleaved h1/h2 column map. gemm2: 128x256, 96KB LDS.

typedef _Float16 half8 __attribute__((ext_vector_type(8)));
typedef _Float16 half4t __attribute__((ext_vector_type(4)));
typedef float f4 __attribute__((ext_vector_type(4)));

#define N_TOK 4096
#define DDIM  768
#define HDIM  2048
#define NEXP  8
#define CAP   614   // int(1.2 * 4096 / 8)
#define CAPP  640

// ---- workspace layout (bytes) ----
#define XH_OFF    0L           // (4097*768) fp16
#define W1T_OFF   6292992L     // [8][4096][768] fp16
#define W2T_OFF   56624640L    // [8][768][2048] fp16
#define ACT_OFF   81790464L    // [16][640][2048] fp16
#define EIDX_OFF  123733504L   // [4096][2] int
#define WTS_OFF   123766272L   // [4096][2] float
#define TOKL_OFF  123799040L   // [16][640] int
#define CNT_OFF   123840000L   // [16] int

__device__ __forceinline__ void gld16(const void* g, void* l) {
  __builtin_amdgcn_global_load_lds(
      (const __attribute__((address_space(1))) unsigned int*)g,
      (__attribute__((address_space(3))) unsigned int*)l, 16, 0, 0);
}

// -------------------- transpose+convert --------------------
// src fp32 [e][R][C] -> dst fp16 [e][C][R]. 64x64 tile through LDS.
__global__ __launch_bounds__(256) void cvt_tr_kernel(const float* __restrict__ src,
                                                     _Float16* __restrict__ dst,
                                                     int R, int C) {
  __shared__ float tile[64 * 69];
  int e = blockIdx.z;
  int r0 = blockIdx.x * 64, c0 = blockIdx.y * 64;
  long sb = (long)e * R * C;
  int t = threadIdx.x;
  int rrow = t >> 4, c4 = (t & 15) * 4;
#pragma unroll
  for (int i = 0; i < 4; i++) {
    int row = i * 16 + rrow;
    f4 v = *(const f4*)(src + sb + (long)(r0 + row) * C + c0 + c4);
    *(f4*)(&tile[row * 69 + c4]) = v;
  }
  __syncthreads();
#pragma unroll
  for (int s = 0; s < 2; s++) {
    int idx = t + s * 256;
    int c = idx >> 3, ch = idx & 7;
    half8 h;
#pragma unroll
    for (int j = 0; j < 8; j++) h[j] = (_Float16)tile[(ch * 8 + j) * 69 + c];
    *(half8*)(dst + sb + (long)(c0 + c) * R + r0 + ch * 8) = h;
  }
}

// -------------------- router (+ x->fp16 convert) --------------------
__global__ __launch_bounds__(256) void router_kernel(const float* __restrict__ x,
                                                     const float* __restrict__ Wg,
                                                     _Float16* __restrict__ xh,
                                                     int* __restrict__ eidx,
                                                     float* __restrict__ wts) {
  __shared__ float wgT[NEXP * DDIM];   // transposed: [e][d] -> conflict-free reads
  int t = threadIdx.x;
  for (int i = t; i < DDIM * NEXP; i += 256) wgT[(i & 7) * DDIM + (i >> 3)] = Wg[i];
  __syncthreads();
  int w = t >> 6, lane = t & 63;
  int tok = blockIdx.x * 4 + w;
  if (tok > N_TOK) return;
  if (tok == N_TOK) {           // zero pad row
    half4t zz; zz[0] = zz[1] = zz[2] = zz[3] = (_Float16)0.f;
#pragma unroll
    for (int j = 0; j < 3; j++) *(half4t*)(xh + (long)N_TOK * DDIM + (lane + j * 64) * 4) = zz;
    return;
  }
  const float* xr = x + (long)tok * DDIM;
#pragma unroll
  for (int j = 0; j < 3; j++) {
    f4 v = *(const f4*)(xr + (lane + j * 64) * 4);
    half4t hv;
    hv[0] = (_Float16)v[0]; hv[1] = (_Float16)v[1];
    hv[2] = (_Float16)v[2]; hv[3] = (_Float16)v[3];
    *(half4t*)(xh + (long)tok * DDIM + (lane + j * 64) * 4) = hv;
  }
  float acc[8] = {0.f, 0.f, 0.f, 0.f, 0.f, 0.f, 0.f, 0.f};
#pragma unroll
  for (int i = 0; i < 12; i++) {
    float xv = xr[i * 64 + lane];
#pragma unroll
    for (int e2 = 0; e2 < 8; e2++) acc[e2] += xv * wgT[e2 * DDIM + i * 64 + lane];
  }
#pragma unroll
  for (int e2 = 0; e2 < 8; e2++) {
    float v = acc[e2];
    v += __shfl_xor(v, 32); v += __shfl_xor(v, 16); v += __shfl_xor(v, 8);
    v += __shfl_xor(v, 4);  v += __shfl_xor(v, 2);  v += __shfl_xor(v, 1);
    acc[e2] = v;
  }
  if (lane == 0) {
    float m0 = -1e30f; int i0 = 0;
#pragma unroll
    for (int e2 = 0; e2 < 8; e2++) if (acc[e2] > m0) { m0 = acc[e2]; i0 = e2; }
    float m1 = -1e30f; int i1 = 0;
#pragma unroll
    for (int e2 = 0; e2 < 8; e2++) if (e2 != i0 && acc[e2] > m1) { m1 = acc[e2]; i1 = e2; }
    float tt = __expf(m1 - m0);
    float w0 = 1.f / (1.f + tt);
    eidx[tok * 2 + 0] = i0; eidx[tok * 2 + 1] = i1;
    wts[tok * 2 + 0] = w0;  wts[tok * 2 + 1] = 1.f - w0;
  }
}

// -------------------- capacity scan (16 blocks, one per (k,e)) --------------------
__global__ __launch_bounds__(64) void scan_kernel(const int* __restrict__ eidx,
                                                  int* __restrict__ toklist,
                                                  int* __restrict__ counts) {
  int z = blockIdx.x;
  int k = z >> 3, e = z & 7;
  int lane = threadIdx.x;
  int mye[64];
#pragma unroll
  for (int c = 0; c < 64; c++) mye[c] = eidx[(c * 64 + lane) * 2 + k];
  int base = 0;
#pragma unroll 4
  for (int c = 0; c < 64; c++) {
    int n = c * 64 + lane;
    bool pred = (mye[c] == e);
    unsigned long long mask = __ballot(pred);
    if (pred) {
      int pos = base + __popcll(mask & ((1ull << lane) - 1ull));
      if (pos < CAP) toklist[z * CAPP + pos] = n;
    }
    base += __popcll(mask);
  }
  if (lane == 0) counts[z] = (base < CAP) ? base : CAP;
}

// -------------------- GEMM1 + fused SwiGLU (pipelined) --------------------
// 256 tokens x 128 h-col pairs (256 virtual cols: 32-col interleave of h1/h2),
// BK=64, 8 waves (2M x 4N), double-buffered LDS (128 KB), counted vmcnt.
__global__ __launch_bounds__(512, 2) void gemm1_kernel(const _Float16* __restrict__ xh,
                                                       const _Float16* __restrict__ w1t,
                                                       const int* __restrict__ toklist,
                                                       const int* __restrict__ counts,
                                                       _Float16* __restrict__ act) {
  int i = blockIdx.x;
  int e = i & 7, j = i >> 3;         // 768 blocks: 96 per XCD, expert-per-XCD
  int m = j % 3, nk = j / 3;         // m innermost: concurrent blocks share B panel
  int k = nk & 1, n = nk >> 1;
  int z = k * 8 + e;
  int count = counts[z];
  int m0 = m * 256;
  if (m0 >= count) return;
  int n0 = n * 128;

  __shared__ _Float16 lds[2][32768];  // [buf][ A 256x64 | B 256x64 ] = 128 KB exactly

  int t = threadIdx.x;
  int u = t & 7, rg = t >> 3;              // rg in 0..63
  int swz = (u ^ (rg & 7)) * 8;            // pre-swizzled global source col

  // token ids for this thread's 4 staging rows -> registers (no LDS, no barrier)
  int tokr[4];
#pragma unroll
  for (int s = 0; s < 4; s++) {
    int r = m0 + s * 64 + rg;
    tokr[s] = (r < count) ? toklist[z * CAPP + r] : N_TOK;   // pad -> zero row
  }

  // stage pointers (at tile 0); each STAGE advances +64 halves
  const _Float16* ag[4];
  const _Float16* bg[4];
  int adst[4], bdst[4];
#pragma unroll
  for (int s = 0; s < 4; s++) {
    int row = s * 64 + rg;
    ag[s] = xh + (long)tokr[s] * DDIM + swz;
    adst[s] = row * 64 + u * 8;
    // B row rb -> h col: 32-col groups, h1/h2 interleaved per 32 rows
    int rb = row;
    int hc = n0 + ((rb >> 6) << 5) + (rb & 31) + ((rb >> 5) & 1) * 2048;
    bg[s] = w1t + ((long)e * 4096 + hc) * DDIM + swz;
    bdst[s] = 16384 + rb * 64 + u * 8;
  }

  int lane = t & 63, wid = t >> 6;
  int wm = wid >> 2, wn = wid & 3;         // 2M x 4N waves; wave owns 128x64
  int q = lane >> 4, m16 = lane & 15;

  f4 zero4 = {0.f, 0.f, 0.f, 0.f};
  f4 acc[8][4];
#pragma unroll
  for (int mt = 0; mt < 8; mt++)
#pragma unroll
    for (int ct = 0; ct < 4; ct++) acc[mt][ct] = zero4;

  // clean vmcnt before the counted pipeline (tok loads retired)
  asm volatile("s_waitcnt vmcnt(0)" ::: "memory");
  __builtin_amdgcn_sched_barrier(0);

  // prologue: stage tile 0 -> buf0, tile 1 -> buf1 (16 loads in flight)
#pragma unroll
  for (int s = 0; s < 4; s++) gld16(ag[s], &lds[0][adst[s]]);
#pragma unroll
  for (int s = 0; s < 4; s++) gld16(bg[s], &lds[0][bdst[s]]);
#pragma unroll
  for (int s = 0; s < 4; s++) gld16(ag[s] + 64, &lds[1][adst[s]]);
#pragma unroll
  for (int s = 0; s < 4; s++) gld16(bg[s] + 64, &lds[1][bdst[s]]);
#pragma unroll
  for (int s = 0; s < 4; s++) { ag[s] += 128; bg[s] += 128; }

  for (int t2 = 0; t2 < 12; t2++) {        // K = 768 = 12 x 64
    int p = t2 & 1;
    const _Float16* A = &lds[p][0];
    const _Float16* B = &lds[p][16384];
    // wait tile t2's 8 loads; keep tile t2+1's 8 in flight (never drain)
    if (t2 < 11) { asm volatile("s_waitcnt vmcnt(8)" ::: "memory"); }
    else         { asm volatile("s_waitcnt vmcnt(0)" ::: "memory"); }
    __builtin_amdgcn_sched_barrier(0);
    __builtin_amdgcn_s_barrier();          // (a) buf p valid for all waves
    __builtin_amdgcn_sched_barrier(0);

#pragma unroll
    for (int kk = 0; kk < 2; kk++) {
      half8 bfr[4];
#pragma unroll
      for (int ct = 0; ct < 4; ct++) {
        int rb = wn * 64 + ct * 16 + m16;
        bfr[ct] = *(const half8*)(B + rb * 64 + (((kk * 4 + q) ^ (rb & 7)) * 8));
      }
      __builtin_amdgcn_s_setprio(1);
#pragma unroll
      for (int mt = 0; mt < 8; mt++) {
        int row = wm * 128 + mt * 16 + m16;
        half8 a = *(const half8*)(A + row * 64 + (((kk * 4 + q) ^ (row & 7)) * 8));
#pragma unroll
        for (int ct = 0; ct < 4; ct++)
          acc[mt][ct] = __builtin_amdgcn_mfma_f32_16x16x32_f16(a, bfr[ct], acc[mt][ct], 0, 0, 0);
      }
      __builtin_amdgcn_s_setprio(0);
    }
    asm volatile("s_waitcnt lgkmcnt(0)" ::: "memory");  // all ds_reads of buf p done
    __builtin_amdgcn_sched_barrier(0);
    __builtin_amdgcn_s_barrier();          // (b) every wave finished reading buf p
    __builtin_amdgcn_sched_barrier(0);
    if (t2 < 10) {                         // stage tile t2+2 into buf p (safe)
#pragma unroll
      for (int s = 0; s < 4; s++) gld16(ag[s], &lds[p][adst[s]]);
#pragma unroll
      for (int s = 0; s < 4; s++) gld16(bg[s], &lds[p][bdst[s]]);
#pragma unroll
      for (int s = 0; s < 4; s++) { ag[s] += 64; bg[s] += 64; }
    }
    __builtin_amdgcn_sched_barrier(0);
  }

  // epilogue: SwiGLU pairing within wave stripe (ct, ct+2 share cols)
  long ab = (long)z * CAPP * HDIM;
#pragma unroll
  for (int mt = 0; mt < 8; mt++) {
    int row0 = m0 + wm * 128 + mt * 16 + q * 4;
#pragma unroll
    for (int cp = 0; cp < 2; cp++) {
      int col = n0 + wn * 32 + cp * 16 + m16;
#pragma unroll
      for (int r = 0; r < 4; r++) {
        int row = row0 + r;
        if (row < CAPP) {
          float h1 = acc[mt][cp][r], h2 = acc[mt][2 + cp][r];
          float s = h2 / (1.f + __expf(-h2));
          act[ab + (long)row * HDIM + col] = (_Float16)(h1 * s);
        }
      }
    }
  }
}

// -------------------- GEMM2 + weighted scatter (pipelined) --------------------
// 128 tokens x 256 out cols, BK=64, 8 waves (2M x 4N), 96 KB LDS, vmcnt(6).
__global__ __launch_bounds__(512, 2) void gemm2_kernel(const _Float16* __restrict__ act,
                                                       const _Float16* __restrict__ w2t,
                                                       const int* __restrict__ toklist,
                                                       const int* __restrict__ counts,
                                                       const float* __restrict__ wts,
                                                       float* __restrict__ out) {
  int i = blockIdx.x;
  int e = i & 7, j = i >> 3;         // 240 blocks, 30/xcd
  int m = j % 5, nk = j / 5;         // nk<6: k=nk&1, n=nk>>1 (0..2)
  int k = nk & 1, n = nk >> 1;
  int z = k * 8 + e;
  int count = counts[z];
  int m0 = m * 128;
  if (m0 >= count) return;
  int n0 = n * 256;

  __shared__ _Float16 lds[2][24576];  // [buf][ A 128x64 | B 256x64 ] = 96 KB
  __shared__ int toksL[128];
  __shared__ float wrow[128];

  int t = threadIdx.x;
  if (t < 128) {
    int r = m0 + t;
    if (r < count) {
      int tok = toklist[z * CAPP + r];
      toksL[t] = tok;
      wrow[t] = wts[tok * 2 + k];
    } else {
      toksL[t] = -1;
      wrow[t] = 0.f;
    }
  }
  __syncthreads();   // drains vmcnt/lgkmcnt: clean slate for counted pipeline

  int u = t & 7, rg = t >> 3;
  int swz = (u ^ (rg & 7)) * 8;

  const _Float16* ag[2];
  const _Float16* bg[4];
  int adst[2], bdst[4];
#pragma unroll
  for (int s = 0; s < 2; s++) {
    int row = s * 64 + rg;
    ag[s] = act + ((long)z * CAPP + m0 + row) * HDIM + swz;
    adst[s] = row * 64 + u * 8;
  }
#pragma unroll
  for (int s = 0; s < 4; s++) {
    int rb = s * 64 + rg;
    bg[s] = w2t + ((long)e * DDIM + n0 + rb) * HDIM + swz;
    bdst[s] = 8192 + rb * 64 + u * 8;
  }

  int lane = t & 63, wid = t >> 6;
  int wm = wid >> 2, wn = wid & 3;        // wave owns 64x64
  int q = lane >> 4, m16 = lane & 15;

  f4 zero4 = {0.f, 0.f, 0.f, 0.f};
  f4 acc[4][4];
#pragma unroll
  for (int mt = 0; mt < 4; mt++)
#pragma unroll
    for (int ct = 0; ct < 4; ct++) acc[mt][ct] = zero4;

  // prologue: tile 0 -> buf0, tile 1 -> buf1 (12 loads in flight)
#pragma unroll
  for (int s = 0; s < 2; s++) gld16(ag[s], &lds[0][adst[s]]);
#pragma unroll
  for (int s = 0; s < 4; s++) gld16(bg[s], &lds[0][bdst[s]]);
#pragma unroll
  for (int s = 0; s < 2; s++) gld16(ag[s] + 64, &lds[1][adst[s]]);
#pragma unroll
  for (int s = 0; s < 4; s++) gld16(bg[s] + 64, &lds[1][bdst[s]]);
#pragma unroll
  for (int s = 0; s < 2; s++) ag[s] += 128;
#pragma unroll
  for (int s = 0; s < 4; s++) bg[s] += 128;

  for (int t2 = 0; t2 < 32; t2++) {       // K = 2048 = 32 x 64
    int p = t2 & 1;
    const _Float16* A = &lds[p][0];
    const _Float16* B = &lds[p][8192];
    if (t2 < 31) { asm volatile("s_waitcnt vmcnt(6)" ::: "memory"); }
    else         { asm volatile("s_waitcnt vmcnt(0)" ::: "memory"); }
    __builtin_amdgcn_sched_barrier(0);
    __builtin_amdgcn_s_barrier();
    __builtin_amdgcn_sched_barrier(0);

#pragma unroll
    for (int kk = 0; kk < 2; kk++) {
      half8 bfr[4];
#pragma unroll
      for (int ct = 0; ct < 4; ct++) {
        int rb = wn * 64 + ct * 16 + m16;
        bfr[ct] = *(const half8*)(B + rb * 64 + (((kk * 4 + q) ^ (rb & 7)) * 8));
      }
      __builtin_amdgcn_s_setprio(1);
#pragma unroll
      for (int mt = 0; mt < 4; mt++) {
        int row = wm * 64 + mt * 16 + m16;
        half8 a = *(const half8*)(A + row * 64 + (((kk * 4 + q) ^ (row & 7)) * 8));
#pragma unroll
        for (int ct = 0; ct < 4; ct++)
          acc[mt][ct] = __builtin_amdgcn_mfma_f32_16x16x32_f16(a, bfr[ct], acc[mt][ct], 0, 0, 0);
      }
      __builtin_amdgcn_s_setprio(0);
    }
    asm volatile("s_waitcnt lgkmcnt(0)" ::: "memory");
    __builtin_amdgcn_sched_barrier(0);
    __builtin_amdgcn_s_barrier();
    __builtin_amdgcn_sched_barrier(0);
    if (t2 < 30) {
#pragma unroll
      for (int s = 0; s < 2; s++) gld16(ag[s], &lds[p][adst[s]]);
#pragma unroll
      for (int s = 0; s < 4; s++) gld16(bg[s], &lds[p][bdst[s]]);
#pragma unroll
      for (int s = 0; s < 2; s++) ag[s] += 64;
#pragma unroll
      for (int s = 0; s < 4; s++) bg[s] += 64;
    }
    __builtin_amdgcn_sched_barrier(0);
  }

  // weighted scatter: out[tok, col] += w * y
#pragma unroll
  for (int mt = 0; mt < 4; mt++)
#pragma unroll
    for (int ct = 0; ct < 4; ct++)
#pragma unroll
      for (int r = 0; r < 4; r++) {
        int lr = wm * 64 + mt * 16 + q * 4 + r;
        int tok = toksL[lr];
        if (tok >= 0) {
          int col = n0 + wn * 64 + ct * 16 + m16;
          atomicAdd(&out[(long)tok * DDIM + col], wrow[lr] * acc[mt][ct][r]);
        }
      }
}

// -------------------- launch --------------------

extern "C" void kernel_launch(void* const* d_in, const int* in_sizes, int n_in,
                              void* d_out, int out_size, void* d_ws, size_t ws_size,
                              hipStream_t stream) {
  const float* x  = (const float*)d_in[0];
  const float* Wg = (const float*)d_in[1];
  const float* W1 = (const float*)d_in[2];
  const float* W2 = (const float*)d_in[3];
  float* out = (float*)d_out;
  char* ws = (char*)d_ws;

  _Float16* xh   = (_Float16*)(ws + XH_OFF);
  _Float16* w1t  = (_Float16*)(ws + W1T_OFF);
  _Float16* w2t  = (_Float16*)(ws + W2T_OFF);
  _Float16* actb = (_Float16*)(ws + ACT_OFF);
  int* eidx      = (int*)(ws + EIDX_OFF);
  float* wts     = (float*)(ws + WTS_OFF);
  int* toklist   = (int*)(ws + TOKL_OFF);
  int* counts    = (int*)(ws + CNT_OFF);

  hipMemsetAsync(d_out, 0, (size_t)out_size * sizeof(float), stream);
  cvt_tr_kernel<<<dim3(12, 64, 8), 256, 0, stream>>>(W1, w1t, 768, 4096);
  cvt_tr_kernel<<<dim3(32, 12, 8), 256, 0, stream>>>(W2, w2t, 2048, 768);
  router_kernel<<<1025, 256, 0, stream>>>(x, Wg, xh, eidx, wts);
  scan_kernel<<<16, 64, 0, stream>>>(eidx, toklist, counts);
  gemm1_kernel<<<768, 512, 0, stream>>>(xh, w1t, toklist, counts, actb);
  gemm2_kernel<<<240, 512, 0, stream>>>(actb, w2t, toklist, counts, wts, out);
}

// Round 3
// 349.719 us; speedup vs baseline: 1.0561x; 1.0561x over previous
//
#include <hip/hip_runtime.h>

// GatedMoE on MI355X (gfx950), fp16 MFMA path, round 7.
// vs r6 (regressed): the 256-row tile wasted 20% MFMA (768 vs 640 rows) and
// the coarse phase split (reads after barrier) left waves in lockstep.
// r7: both GEMMs on the m201-style fine-phase schedule at BM=128/BN=256
// (zero row waste): 3-buffer LDS ring (144 KB), prefetch distance 2 tiles,
// vmcnt(6) once per K-tile (never drains), per-phase {ds_reads issued
// BEFORE barrier || 3 gld16 -> barrier -> lgkmcnt(0) -> setprio(1) +
// 16 MFMA + setprio(0) -> barrier}. B fragments register-resident per tile.

typedef _Float16 half8 __attribute__((ext_vector_type(8)));
typedef _Float16 half4t __attribute__((ext_vector_type(4)));
typedef float f4 __attribute__((ext_vector_type(4)));

#define N_TOK 4096
#define DDIM  768
#define HDIM  2048
#define NEXP  8
#define CAP   614   // int(1.2 * 4096 / 8)
#define CAPP  640

// ---- workspace layout (bytes) ----
#define XH_OFF    0L           // (4097*768) fp16
#define W1T_OFF   6292992L     // [8][4096][768] fp16
#define W2T_OFF   56624640L    // [8][768][2048] fp16
#define ACT_OFF   81790464L    // [16][640][2048] fp16
#define EIDX_OFF  123733504L   // [4096][2] int
#define WTS_OFF   123766272L   // [4096][2] float
#define TOKL_OFF  123799040L   // [16][640] int
#define CNT_OFF   123840000L   // [16] int

#define BUFH 24576             // halves per ring buffer: A 128x64 + B 256x64

__device__ __forceinline__ void gld16(const void* g, void* l) {
  __builtin_amdgcn_global_load_lds(
      (const __attribute__((address_space(1))) unsigned int*)g,
      (__attribute__((address_space(3))) unsigned int*)l, 16, 0, 0);
}

// -------------------- transpose+convert --------------------
__global__ __launch_bounds__(256) void cvt_tr_kernel(const float* __restrict__ src,
                                                     _Float16* __restrict__ dst,
                                                     int R, int C) {
  __shared__ float tile[64 * 69];
  int e = blockIdx.z;
  int r0 = blockIdx.x * 64, c0 = blockIdx.y * 64;
  long sb = (long)e * R * C;
  int t = threadIdx.x;
  int rrow = t >> 4, c4 = (t & 15) * 4;
#pragma unroll
  for (int i = 0; i < 4; i++) {
    int row = i * 16 + rrow;
    f4 v = *(const f4*)(src + sb + (long)(r0 + row) * C + c0 + c4);
    *(f4*)(&tile[row * 69 + c4]) = v;
  }
  __syncthreads();
#pragma unroll
  for (int s = 0; s < 2; s++) {
    int idx = t + s * 256;
    int c = idx >> 3, ch = idx & 7;
    half8 h;
#pragma unroll
    for (int j = 0; j < 8; j++) h[j] = (_Float16)tile[(ch * 8 + j) * 69 + c];
    *(half8*)(dst + sb + (long)(c0 + c) * R + r0 + ch * 8) = h;
  }
}

// -------------------- router (+ x->fp16 convert) --------------------
__global__ __launch_bounds__(256) void router_kernel(const float* __restrict__ x,
                                                     const float* __restrict__ Wg,
                                                     _Float16* __restrict__ xh,
                                                     int* __restrict__ eidx,
                                                     float* __restrict__ wts) {
  __shared__ float wgT[NEXP * DDIM];   // transposed: [e][d]
  int t = threadIdx.x;
  for (int i = t; i < DDIM * NEXP; i += 256) wgT[(i & 7) * DDIM + (i >> 3)] = Wg[i];
  __syncthreads();
  int w = t >> 6, lane = t & 63;
  int tok = blockIdx.x * 4 + w;
  if (tok > N_TOK) return;
  if (tok == N_TOK) {           // zero pad row
    half4t zz; zz[0] = zz[1] = zz[2] = zz[3] = (_Float16)0.f;
#pragma unroll
    for (int j = 0; j < 3; j++) *(half4t*)(xh + (long)N_TOK * DDIM + (lane + j * 64) * 4) = zz;
    return;
  }
  const float* xr = x + (long)tok * DDIM;
#pragma unroll
  for (int j = 0; j < 3; j++) {
    f4 v = *(const f4*)(xr + (lane + j * 64) * 4);
    half4t hv;
    hv[0] = (_Float16)v[0]; hv[1] = (_Float16)v[1];
    hv[2] = (_Float16)v[2]; hv[3] = (_Float16)v[3];
    *(half4t*)(xh + (long)tok * DDIM + (lane + j * 64) * 4) = hv;
  }
  float acc[8] = {0.f, 0.f, 0.f, 0.f, 0.f, 0.f, 0.f, 0.f};
#pragma unroll
  for (int i = 0; i < 12; i++) {
    float xv = xr[i * 64 + lane];
#pragma unroll
    for (int e2 = 0; e2 < 8; e2++) acc[e2] += xv * wgT[e2 * DDIM + i * 64 + lane];
  }
#pragma unroll
  for (int e2 = 0; e2 < 8; e2++) {
    float v = acc[e2];
    v += __shfl_xor(v, 32); v += __shfl_xor(v, 16); v += __shfl_xor(v, 8);
    v += __shfl_xor(v, 4);  v += __shfl_xor(v, 2);  v += __shfl_xor(v, 1);
    acc[e2] = v;
  }
  if (lane == 0) {
    float m0 = -1e30f; int i0 = 0;
#pragma unroll
    for (int e2 = 0; e2 < 8; e2++) if (acc[e2] > m0) { m0 = acc[e2]; i0 = e2; }
    float m1 = -1e30f; int i1 = 0;
#pragma unroll
    for (int e2 = 0; e2 < 8; e2++) if (e2 != i0 && acc[e2] > m1) { m1 = acc[e2]; i1 = e2; }
    float tt = __expf(m1 - m0);
    float w0 = 1.f / (1.f + tt);
    eidx[tok * 2 + 0] = i0; eidx[tok * 2 + 1] = i1;
    wts[tok * 2 + 0] = w0;  wts[tok * 2 + 1] = 1.f - w0;
  }
}

// -------------------- capacity scan --------------------
__global__ __launch_bounds__(64) void scan_kernel(const int* __restrict__ eidx,
                                                  int* __restrict__ toklist,
                                                  int* __restrict__ counts) {
  int z = blockIdx.x;
  int k = z >> 3, e = z & 7;
  int lane = threadIdx.x;
  int mye[64];
#pragma unroll
  for (int c = 0; c < 64; c++) mye[c] = eidx[(c * 64 + lane) * 2 + k];
  int base = 0;
#pragma unroll 4
  for (int c = 0; c < 64; c++) {
    int n = c * 64 + lane;
    bool pred = (mye[c] == e);
    unsigned long long mask = __ballot(pred);
    if (pred) {
      int pos = base + __popcll(mask & ((1ull << lane) - 1ull));
      if (pos < CAP) toklist[z * CAPP + pos] = n;
    }
    base += __popcll(mask);
  }
  if (lane == 0) counts[z] = (base < CAP) ? base : CAP;
}

// -------------------- GEMM1 + fused SwiGLU (fine-phase pipeline) --------------------
// 128 tokens x 256 virtual cols (128 h1 + 128 h2 interleaved), BK=64,
// 8 waves (2M x 4N, wave = 64x64), 3-buffer LDS ring, vmcnt(6)/tile.
__global__ __launch_bounds__(512, 2) void gemm1_kernel(const _Float16* __restrict__ xh,
                                                       const _Float16* __restrict__ w1t,
                                                       const int* __restrict__ toklist,
                                                       const int* __restrict__ counts,
                                                       _Float16* __restrict__ act) {
  int i = blockIdx.x;
  int e = i & 7, j = i >> 3;         // 1280 blocks: 160/XCD, expert-per-XCD
  int m = j % 5, nk = j / 5;         // m innermost: 5 m-blocks share B panel
  int k = nk & 1, n = nk >> 1;       // n in 0..15
  int z = k * 8 + e;
  int count = counts[z];
  int m0 = m * 128;
  if (m0 >= count) return;
  int n0 = n * 128;

  __shared__ _Float16 lds[3 * BUFH];  // 144 KB ring

  int t = threadIdx.x;
  int u = t & 7, rg = t >> 3;              // rg in 0..63
  int swz = (u ^ (rg & 7)) * 8;            // pre-swizzled global source col

  int tokr[2];
#pragma unroll
  for (int s = 0; s < 2; s++) {
    int r = m0 + s * 64 + rg;
    tokr[s] = (r < count) ? toklist[z * CAPP + r] : N_TOK;
  }

  const _Float16* ag[2]; int adst[2];
#pragma unroll
  for (int s = 0; s < 2; s++) {
    int row = s * 64 + rg;
    ag[s] = xh + (long)tokr[s] * DDIM + swz;
    adst[s] = row * 64 + u * 8;
  }
  const _Float16* bg[4]; int bdst[4];
#pragma unroll
  for (int s = 0; s < 4; s++) {
    int rb = s * 64 + rg;
    int hc = n0 + ((rb >> 6) << 5) + (rb & 31) + ((rb >> 5) & 1) * 2048;
    bg[s] = w1t + ((long)e * 4096 + hc) * DDIM + swz;
    bdst[s] = 8192 + rb * 64 + u * 8;
  }

  int lane = t & 63, wid = t >> 6;
  int wm = wid >> 2, wn = wid & 3;         // wave owns 64 rows x 64 vcols
  int q = lane >> 4, m16 = lane & 15;

  f4 zero4 = {0.f, 0.f, 0.f, 0.f};
  f4 acc[4][4];
#pragma unroll
  for (int mt = 0; mt < 4; mt++)
#pragma unroll
    for (int ct = 0; ct < 4; ct++) acc[mt][ct] = zero4;

  asm volatile("s_waitcnt vmcnt(0)" ::: "memory");   // tok loads retired
  __builtin_amdgcn_sched_barrier(0);

  // prologue: tile0 -> buf0, tile1 -> buf1 (12 loads)
#pragma unroll
  for (int s = 0; s < 2; s++) gld16(ag[s], &lds[adst[s]]);
#pragma unroll
  for (int s = 0; s < 4; s++) gld16(bg[s], &lds[bdst[s]]);
#pragma unroll
  for (int s = 0; s < 2; s++) gld16(ag[s] + 64, &lds[BUFH + adst[s]]);
#pragma unroll
  for (int s = 0; s < 4; s++) gld16(bg[s] + 64, &lds[BUFH + bdst[s]]);
#pragma unroll
  for (int s = 0; s < 2; s++) ag[s] += 128;
#pragma unroll
  for (int s = 0; s < 4; s++) bg[s] += 128;
  asm volatile("s_waitcnt vmcnt(6)" ::: "memory");   // tile0 done, tile1 in flight
  __builtin_amdgcn_sched_barrier(0);
  __builtin_amdgcn_s_barrier();
  __builtin_amdgcn_sched_barrier(0);

  int offR = 0, offM = BUFH, offW = 2 * BUFH;

  for (int t2 = 0; t2 < 12; t2++) {        // K = 768 = 12 x 64
    const _Float16* A = &lds[offR];
    const _Float16* B = &lds[offR + 8192];
    bool st = (t2 < 10);

    // ---- phase 0: reads issued BEFORE barrier; MFMA mt 0..1 ----
    half8 bfr[4][2], afr[2][2];
#pragma unroll
    for (int ct = 0; ct < 4; ct++) {
      int rb = wn * 64 + ct * 16 + m16;
      bfr[ct][0] = *(const half8*)(B + rb * 64 + (((0 * 4 + q) ^ (rb & 7)) * 8));
      bfr[ct][1] = *(const half8*)(B + rb * 64 + (((1 * 4 + q) ^ (rb & 7)) * 8));
    }
#pragma unroll
    for (int mt = 0; mt < 2; mt++) {
      int row = wm * 64 + mt * 16 + m16;
      afr[mt][0] = *(const half8*)(A + row * 64 + (((0 * 4 + q) ^ (row & 7)) * 8));
      afr[mt][1] = *(const half8*)(A + row * 64 + (((1 * 4 + q) ^ (row & 7)) * 8));
    }
    if (st) {
      gld16(ag[0], &lds[offW + adst[0]]);
      gld16(ag[1], &lds[offW + adst[1]]);
      gld16(bg[0], &lds[offW + bdst[0]]);
    }
    __builtin_amdgcn_sched_barrier(0);
    __builtin_amdgcn_s_barrier();
    __builtin_amdgcn_sched_barrier(0);
    asm volatile("s_waitcnt lgkmcnt(0)" ::: "memory");
    __builtin_amdgcn_sched_barrier(0);
    __builtin_amdgcn_s_setprio(1);
#pragma unroll
    for (int mt = 0; mt < 2; mt++)
#pragma unroll
      for (int ct = 0; ct < 4; ct++) {
        acc[mt][ct] = __builtin_amdgcn_mfma_f32_16x16x32_f16(afr[mt][0], bfr[ct][0], acc[mt][ct], 0, 0, 0);
        acc[mt][ct] = __builtin_amdgcn_mfma_f32_16x16x32_f16(afr[mt][1], bfr[ct][1], acc[mt][ct], 0, 0, 0);
      }
    __builtin_amdgcn_s_setprio(0);
    __builtin_amdgcn_sched_barrier(0);
    __builtin_amdgcn_s_barrier();
    __builtin_amdgcn_sched_barrier(0);

    // ---- phase 1: A mt 2..3 reads; B stays in regs ----
    half8 afr2[2][2];
#pragma unroll
    for (int mt = 0; mt < 2; mt++) {
      int row = wm * 64 + (2 + mt) * 16 + m16;
      afr2[mt][0] = *(const half8*)(A + row * 64 + (((0 * 4 + q) ^ (row & 7)) * 8));
      afr2[mt][1] = *(const half8*)(A + row * 64 + (((1 * 4 + q) ^ (row & 7)) * 8));
    }
    if (st) {
      gld16(bg[1], &lds[offW + bdst[1]]);
      gld16(bg[2], &lds[offW + bdst[2]]);
      gld16(bg[3], &lds[offW + bdst[3]]);
#pragma unroll
      for (int s = 0; s < 2; s++) ag[s] += 64;
#pragma unroll
      for (int s = 0; s < 4; s++) bg[s] += 64;
    }
    __builtin_amdgcn_sched_barrier(0);
    __builtin_amdgcn_s_barrier();
    __builtin_amdgcn_sched_barrier(0);
    asm volatile("s_waitcnt lgkmcnt(0)" ::: "memory");
    __builtin_amdgcn_sched_barrier(0);
    __builtin_amdgcn_s_setprio(1);
#pragma unroll
    for (int mt = 0; mt < 2; mt++)
#pragma unroll
      for (int ct = 0; ct < 4; ct++) {
        acc[2 + mt][ct] = __builtin_amdgcn_mfma_f32_16x16x32_f16(afr2[mt][0], bfr[ct][0], acc[2 + mt][ct], 0, 0, 0);
        acc[2 + mt][ct] = __builtin_amdgcn_mfma_f32_16x16x32_f16(afr2[mt][1], bfr[ct][1], acc[2 + mt][ct], 0, 0, 0);
      }
    __builtin_amdgcn_s_setprio(0);
    __builtin_amdgcn_sched_barrier(0);
    if (t2 < 10)      { asm volatile("s_waitcnt vmcnt(6)" ::: "memory"); }
    else if (t2 == 10){ asm volatile("s_waitcnt vmcnt(0)" ::: "memory"); }
    if (t2 < 11) {
      __builtin_amdgcn_sched_barrier(0);
      __builtin_amdgcn_s_barrier();
      __builtin_amdgcn_sched_barrier(0);
    }
    int tmp = offR; offR = offM; offM = offW; offW = tmp;   // rotate ring
  }

  // epilogue: SwiGLU pairing (vcol ct and ct+2 share h-col, bit5 = h1/h2)
  long ab = (long)z * CAPP * HDIM;
#pragma unroll
  for (int mt = 0; mt < 4; mt++) {
    int row0 = m0 + wm * 64 + mt * 16 + q * 4;
#pragma unroll
    for (int cp = 0; cp < 2; cp++) {
      int col = n0 + wn * 32 + cp * 16 + m16;
#pragma unroll
      for (int r = 0; r < 4; r++) {
        int row = row0 + r;
        float h1 = acc[mt][cp][r], h2 = acc[mt][2 + cp][r];
        float s = h2 / (1.f + __expf(-h2));
        act[ab + (long)row * HDIM + col] = (_Float16)(h1 * s);
      }
    }
  }
}

// -------------------- GEMM2 + weighted scatter (fine-phase pipeline) --------------------
// 128 tokens x 256 out cols, BK=64, 8 waves (2M x 4N), 3-buffer ring, vmcnt(6)/tile.
__global__ __launch_bounds__(512, 2) void gemm2_kernel(const _Float16* __restrict__ act,
                                                       const _Float16* __restrict__ w2t,
                                                       const int* __restrict__ toklist,
                                                       const int* __restrict__ counts,
                                                       const float* __restrict__ wts,
                                                       float* __restrict__ out) {
  int i = blockIdx.x;
  int e = i & 7, j = i >> 3;         // 240 blocks, 30/XCD
  int m = j % 5, nk = j / 5;         // nk<6: k=nk&1, n=nk>>1 (0..2)
  int k = nk & 1, n = nk >> 1;
  int z = k * 8 + e;
  int count = counts[z];
  int m0 = m * 128;
  if (m0 >= count) return;
  int n0 = n * 256;

  __shared__ _Float16 lds[3 * BUFH];  // 144 KB ring
  __shared__ int toksL[128];
  __shared__ float wrow[128];

  int t = threadIdx.x;
  if (t < 128) {
    int r = m0 + t;
    if (r < count) {
      int tok = toklist[z * CAPP + r];
      toksL[t] = tok;
      wrow[t] = wts[tok * 2 + k];
    } else {
      toksL[t] = -1;
      wrow[t] = 0.f;
    }
  }
  __syncthreads();   // toksL/wrow visible; also drains counters

  int u = t & 7, rg = t >> 3;
  int swz = (u ^ (rg & 7)) * 8;

  const _Float16* ag[2]; int adst[2];
#pragma unroll
  for (int s = 0; s < 2; s++) {
    int row = s * 64 + rg;
    ag[s] = act + ((long)z * CAPP + m0 + row) * HDIM + swz;
    adst[s] = row * 64 + u * 8;
  }
  const _Float16* bg[4]; int bdst[4];
#pragma unroll
  for (int s = 0; s < 4; s++) {
    int rb = s * 64 + rg;
    bg[s] = w2t + ((long)e * DDIM + n0 + rb) * HDIM + swz;
    bdst[s] = 8192 + rb * 64 + u * 8;
  }

  int lane = t & 63, wid = t >> 6;
  int wm = wid >> 2, wn = wid & 3;        // wave owns 64x64
  int q = lane >> 4, m16 = lane & 15;

  f4 zero4 = {0.f, 0.f, 0.f, 0.f};
  f4 acc[4][4];
#pragma unroll
  for (int mt = 0; mt < 4; mt++)
#pragma unroll
    for (int ct = 0; ct < 4; ct++) acc[mt][ct] = zero4;

  // prologue: tile0 -> buf0, tile1 -> buf1
#pragma unroll
  for (int s = 0; s < 2; s++) gld16(ag[s], &lds[adst[s]]);
#pragma unroll
  for (int s = 0; s < 4; s++) gld16(bg[s], &lds[bdst[s]]);
#pragma unroll
  for (int s = 0; s < 2; s++) gld16(ag[s] + 64, &lds[BUFH + adst[s]]);
#pragma unroll
  for (int s = 0; s < 4; s++) gld16(bg[s] + 64, &lds[BUFH + bdst[s]]);
#pragma unroll
  for (int s = 0; s < 2; s++) ag[s] += 128;
#pragma unroll
  for (int s = 0; s < 4; s++) bg[s] += 128;
  asm volatile("s_waitcnt vmcnt(6)" ::: "memory");
  __builtin_amdgcn_sched_barrier(0);
  __builtin_amdgcn_s_barrier();
  __builtin_amdgcn_sched_barrier(0);

  int offR = 0, offM = BUFH, offW = 2 * BUFH;

  for (int t2 = 0; t2 < 32; t2++) {       // K = 2048 = 32 x 64
    const _Float16* A = &lds[offR];
    const _Float16* B = &lds[offR + 8192];
    bool st = (t2 < 30);

    // ---- phase 0 ----
    half8 bfr[4][2], afr[2][2];
#pragma unroll
    for (int ct = 0; ct < 4; ct++) {
      int rb = wn * 64 + ct * 16 + m16;
      bfr[ct][0] = *(const half8*)(B + rb * 64 + (((0 * 4 + q) ^ (rb & 7)) * 8));
      bfr[ct][1] = *(const half8*)(B + rb * 64 + (((1 * 4 + q) ^ (rb & 7)) * 8));
    }
#pragma unroll
    for (int mt = 0; mt < 2; mt++) {
      int row = wm * 64 + mt * 16 + m16;
      afr[mt][0] = *(const half8*)(A + row * 64 + (((0 * 4 + q) ^ (row & 7)) * 8));
      afr[mt][1] = *(const half8*)(A + row * 64 + (((1 * 4 + q) ^ (row & 7)) * 8));
    }
    if (st) {
      gld16(ag[0], &lds[offW + adst[0]]);
      gld16(ag[1], &lds[offW + adst[1]]);
      gld16(bg[0], &lds[offW + bdst[0]]);
    }
    __builtin_amdgcn_sched_barrier(0);
    __builtin_amdgcn_s_barrier();
    __builtin_amdgcn_sched_barrier(0);
    asm volatile("s_waitcnt lgkmcnt(0)" ::: "memory");
    __builtin_amdgcn_sched_barrier(0);
    __builtin_amdgcn_s_setprio(1);
#pragma unroll
    for (int mt = 0; mt < 2; mt++)
#pragma unroll
      for (int ct = 0; ct < 4; ct++) {
        acc[mt][ct] = __builtin_amdgcn_mfma_f32_16x16x32_f16(afr[mt][0], bfr[ct][0], acc[mt][ct], 0, 0, 0);
        acc[mt][ct] = __builtin_amdgcn_mfma_f32_16x16x32_f16(afr[mt][1], bfr[ct][1], acc[mt][ct], 0, 0, 0);
      }
    __builtin_amdgcn_s_setprio(0);
    __builtin_amdgcn_sched_barrier(0);
    __builtin_amdgcn_s_barrier();
    __builtin_amdgcn_sched_barrier(0);

    // ---- phase 1 ----
    half8 afr2[2][2];
#pragma unroll
    for (int mt = 0; mt < 2; mt++) {
      int row = wm * 64 + (2 + mt) * 16 + m16;
      afr2[mt][0] = *(const half8*)(A + row * 64 + (((0 * 4 + q) ^ (row & 7)) * 8));
      afr2[mt][1] = *(const half8*)(A + row * 64 + (((1 * 4 + q) ^ (row & 7)) * 8));
    }
    if (st) {
      gld16(bg[1], &lds[offW + bdst[1]]);
      gld16(bg[2], &lds[offW + bdst[2]]);
      gld16(bg[3], &lds[offW + bdst[3]]);
#pragma unroll
      for (int s = 0; s < 2; s++) ag[s] += 64;
#pragma unroll
      for (int s = 0; s < 4; s++) bg[s] += 64;
    }
    __builtin_amdgcn_sched_barrier(0);
    __builtin_amdgcn_s_barrier();
    __builtin_amdgcn_sched_barrier(0);
    asm volatile("s_waitcnt lgkmcnt(0)" ::: "memory");
    __builtin_amdgcn_sched_barrier(0);
    __builtin_amdgcn_s_setprio(1);
#pragma unroll
    for (int mt = 0; mt < 2; mt++)
#pragma unroll
      for (int ct = 0; ct < 4; ct++) {
        acc[2 + mt][ct] = __builtin_amdgcn_mfma_f32_16x16x32_f16(afr2[mt][0], bfr[ct][0], acc[2 + mt][ct], 0, 0, 0);
        acc[2 + mt][ct] = __builtin_amdgcn_mfma_f32_16x16x32_f16(afr2[mt][1], bfr[ct][1], acc[2 + mt][ct], 0, 0, 0);
      }
    __builtin_amdgcn_s_setprio(0);
    __builtin_amdgcn_sched_barrier(0);
    if (t2 < 30)      { asm volatile("s_waitcnt vmcnt(6)" ::: "memory"); }
    else if (t2 == 30){ asm volatile("s_waitcnt vmcnt(0)" ::: "memory"); }
    if (t2 < 31) {
      __builtin_amdgcn_sched_barrier(0);
      __builtin_amdgcn_s_barrier();
      __builtin_amdgcn_sched_barrier(0);
    }
    int tmp = offR; offR = offM; offM = offW; offW = tmp;
  }

  // weighted scatter: out[tok, col] += w * y
#pragma unroll
  for (int mt = 0; mt < 4; mt++)
#pragma unroll
    for (int ct = 0; ct < 4; ct++)
#pragma unroll
      for (int r = 0; r < 4; r++) {
        int lr = wm * 64 + mt * 16 + q * 4 + r;
        int tok = toksL[lr];
        if (tok >= 0) {
          int col = n0 + wn * 64 + ct * 16 + m16;
          atomicAdd(&out[(long)tok * DDIM + col], wrow[lr] * acc[mt][ct][r]);
        }
      }
}

// -------------------- launch --------------------

extern "C" void kernel_launch(void* const* d_in, const int* in_sizes, int n_in,
                              void* d_out, int out_size, void* d_ws, size_t ws_size,
                              hipStream_t stream) {
  const float* x  = (const float*)d_in[0];
  const float* Wg = (const float*)d_in[1];
  const float* W1 = (const float*)d_in[2];
  const float* W2 = (const float*)d_in[3];
  float* out = (float*)d_out;
  char* ws = (char*)d_ws;

  _Float16* xh   = (_Float16*)(ws + XH_OFF);
  _Float16* w1t  = (_Float16*)(ws + W1T_OFF);
  _Float16* w2t  = (_Float16*)(ws + W2T_OFF);
  _Float16* actb = (_Float16*)(ws + ACT_OFF);
  int* eidx      = (int*)(ws + EIDX_OFF);
  float* wts     = (float*)(ws + WTS_OFF);
  int* toklist   = (int*)(ws + TOKL_OFF);
  int* counts    = (int*)(ws + CNT_OFF);

  hipMemsetAsync(d_out, 0, (size_t)out_size * sizeof(float), stream);
  cvt_tr_kernel<<<dim3(12, 64, 8), 256, 0, stream>>>(W1, w1t, 768, 4096);
  cvt_tr_kernel<<<dim3(32, 12, 8), 256, 0, stream>>>(W2, w2t, 2048, 768);
  router_kernel<<<1025, 256, 0, stream>>>(x, Wg, xh, eidx, wts);
  scan_kernel<<<16, 64, 0, stream>>>(eidx, toklist, counts);
  gemm1_kernel<<<1280, 512, 0, stream>>>(xh, w1t, toklist, counts, actb);
  gemm2_kernel<<<240, 512, 0, stream>>>(actb, w2t, toklist, counts, wts, out);
}

// Round 4
// 341.883 us; speedup vs baseline: 1.0803x; 1.0229x over previous
//
#include <hip/hip_runtime.h>

// GatedMoE on MI355X (gfx950), fp16 MFMA path, round 8.
// Lesson r6/r7: explicit pipelines at 1 block/CU LOSE to r4's plain
// 2-barrier loop at 3 blocks/CU (TLP > scheduling at this geometry).
// r8 = r4's verified GEMMs (75.1us gemm1) + prep fusion: cvt_tr(W1) +
// cvt_tr(W2) + router merged into ONE launch (block-range dispatch),
// cutting 7 dispatches to 5 and overlapping the conversion tails with
// the router. Router keeps transposed wgT (conflict-free).

typedef _Float16 half8 __attribute__((ext_vector_type(8)));
typedef _Float16 half4t __attribute__((ext_vector_type(4)));
typedef float f4 __attribute__((ext_vector_type(4)));

#define N_TOK 4096
#define DDIM  768
#define HDIM  2048
#define NEXP  8
#define CAP   614   // int(1.2 * 4096 / 8)
#define CAPP  640

// ---- workspace layout (bytes) ----
#define XH_OFF    0L           // (4097*768) fp16
#define W1T_OFF   6292992L     // [8][4096][768] fp16
#define W2T_OFF   56624640L    // [8][768][2048] fp16
#define ACT_OFF   81790464L    // [16][640][2048] fp16
#define EIDX_OFF  123733504L   // [4096][2] int
#define WTS_OFF   123766272L   // [4096][2] float
#define TOKL_OFF  123799040L   // [16][640] int
#define CNT_OFF   123840000L   // [16] int

__device__ __forceinline__ void gld16(const void* g, void* l) {
  __builtin_amdgcn_global_load_lds(
      (const __attribute__((address_space(1))) unsigned int*)g,
      (__attribute__((address_space(3))) unsigned int*)l, 16, 0, 0);
}

// -------------------- fused prep: cvt_tr(W1) | cvt_tr(W2) | router --------------------
// blocks [0,6144): W1 [8][768][4096] fp32 -> w1t [8][4096][768] fp16
// blocks [6144,9216): W2 [8][2048][768] fp32 -> w2t [8][768][2048] fp16
// blocks [9216,10241): router + x->fp16 convert (4 tokens/block)

__device__ __forceinline__ void cvt_tile(const float* __restrict__ src,
                                         _Float16* __restrict__ dst,
                                         int R, int C, int e, int r0, int c0,
                                         float* tile) {
  long sb = (long)e * R * C;
  int t = threadIdx.x;
  int rrow = t >> 4, c4 = (t & 15) * 4;
#pragma unroll
  for (int i = 0; i < 4; i++) {
    int row = i * 16 + rrow;
    f4 v = *(const f4*)(src + sb + (long)(r0 + row) * C + c0 + c4);
    *(f4*)(&tile[row * 69 + c4]) = v;
  }
  __syncthreads();
#pragma unroll
  for (int s = 0; s < 2; s++) {
    int idx = t + s * 256;
    int c = idx >> 3, ch = idx & 7;
    half8 h;
#pragma unroll
    for (int j = 0; j < 8; j++) h[j] = (_Float16)tile[(ch * 8 + j) * 69 + c];
    *(half8*)(dst + sb + (long)(c0 + c) * R + r0 + ch * 8) = h;
  }
}

__global__ __launch_bounds__(256) void prep_kernel(const float* __restrict__ W1,
                                                   const float* __restrict__ W2,
                                                   const float* __restrict__ x,
                                                   const float* __restrict__ Wg,
                                                   _Float16* __restrict__ w1t,
                                                   _Float16* __restrict__ w2t,
                                                   _Float16* __restrict__ xh,
                                                   int* __restrict__ eidx,
                                                   float* __restrict__ wts) {
  __shared__ float smem[NEXP * DDIM];   // 24 KB: cvt tile (17.3 KB) or wgT
  int b = blockIdx.x;

  if (b < 6144) {                        // ---- cvt W1: 768 x 4096 per expert
    int e = b / 768, rem = b % 768;
    int cy = rem / 12, cx = rem % 12;    // cx: R/64=12, cy: C/64=64
    cvt_tile(W1, w1t, 768, 4096, e, cx * 64, cy * 64, smem);
    return;
  }
  if (b < 9216) {                        // ---- cvt W2: 2048 x 768 per expert
    int b2 = b - 6144;
    int e = b2 / 384, rem = b2 % 384;
    int cy = rem / 32, cx = rem % 32;    // cx: R/64=32, cy: C/64=12
    cvt_tile(W2, w2t, 2048, 768, e, cx * 64, cy * 64, smem);
    return;
  }

  // ---- router (block-uniform path)
  int rb = b - 9216;                     // 0..1024
  int t = threadIdx.x;
  for (int i = t; i < DDIM * NEXP; i += 256) smem[(i & 7) * DDIM + (i >> 3)] = Wg[i];
  __syncthreads();
  int w = t >> 6, lane = t & 63;
  int tok = rb * 4 + w;
  if (tok > N_TOK) return;
  if (tok == N_TOK) {                    // zero pad row
    half4t zz; zz[0] = zz[1] = zz[2] = zz[3] = (_Float16)0.f;
#pragma unroll
    for (int j = 0; j < 3; j++) *(half4t*)(xh + (long)N_TOK * DDIM + (lane + j * 64) * 4) = zz;
    return;
  }
  const float* xr = x + (long)tok * DDIM;
#pragma unroll
  for (int j = 0; j < 3; j++) {
    f4 v = *(const f4*)(xr + (lane + j * 64) * 4);
    half4t hv;
    hv[0] = (_Float16)v[0]; hv[1] = (_Float16)v[1];
    hv[2] = (_Float16)v[2]; hv[3] = (_Float16)v[3];
    *(half4t*)(xh + (long)tok * DDIM + (lane + j * 64) * 4) = hv;
  }
  float acc[8] = {0.f, 0.f, 0.f, 0.f, 0.f, 0.f, 0.f, 0.f};
#pragma unroll
  for (int i = 0; i < 12; i++) {
    float xv = xr[i * 64 + lane];
#pragma unroll
    for (int e2 = 0; e2 < 8; e2++) acc[e2] += xv * smem[e2 * DDIM + i * 64 + lane];
  }
#pragma unroll
  for (int e2 = 0; e2 < 8; e2++) {
    float v = acc[e2];
    v += __shfl_xor(v, 32); v += __shfl_xor(v, 16); v += __shfl_xor(v, 8);
    v += __shfl_xor(v, 4);  v += __shfl_xor(v, 2);  v += __shfl_xor(v, 1);
    acc[e2] = v;
  }
  if (lane == 0) {
    float m0 = -1e30f; int i0 = 0;
#pragma unroll
    for (int e2 = 0; e2 < 8; e2++) if (acc[e2] > m0) { m0 = acc[e2]; i0 = e2; }
    float m1 = -1e30f; int i1 = 0;
#pragma unroll
    for (int e2 = 0; e2 < 8; e2++) if (e2 != i0 && acc[e2] > m1) { m1 = acc[e2]; i1 = e2; }
    float tt = __expf(m1 - m0);
    float w0 = 1.f / (1.f + tt);
    eidx[tok * 2 + 0] = i0; eidx[tok * 2 + 1] = i1;
    wts[tok * 2 + 0] = w0;  wts[tok * 2 + 1] = 1.f - w0;
  }
}

// -------------------- capacity scan (16 blocks, one per (k,e)) --------------------
__global__ __launch_bounds__(64) void scan_kernel(const int* __restrict__ eidx,
                                                  int* __restrict__ toklist,
                                                  int* __restrict__ counts) {
  int z = blockIdx.x;
  int k = z >> 3, e = z & 7;
  int lane = threadIdx.x;
  int mye[64];
#pragma unroll
  for (int c = 0; c < 64; c++) mye[c] = eidx[(c * 64 + lane) * 2 + k];
  int base = 0;
#pragma unroll 4
  for (int c = 0; c < 64; c++) {
    int n = c * 64 + lane;
    bool pred = (mye[c] == e);
    unsigned long long mask = __ballot(pred);
    if (pred) {
      int pos = base + __popcll(mask & ((1ull << lane) - 1ull));
      if (pos < CAP) toklist[z * CAPP + pos] = n;
    }
    base += __popcll(mask);
  }
  if (lane == 0) counts[z] = (base < CAP) ? base : CAP;
}

// -------------------- GEMM1 + fused SwiGLU (r4 structure: 3 blocks/CU) --------------------
// Tile 128 tokens x 128 act cols (256 B rows: h1+h2), BK=64, single-buffered.
__global__ __launch_bounds__(256, 2) void gemm1_kernel(const _Float16* __restrict__ xh,
                                                       const _Float16* __restrict__ w1t,
                                                       const int* __restrict__ toklist,
                                                       const int* __restrict__ counts,
                                                       _Float16* __restrict__ act) {
  int i = blockIdx.x;
  int xcd = i & 7, j = i >> 3;       // 1280 blocks, 160/xcd
  int m = j % 5, ii = j / 5;
  int k = ii & 1, n = ii >> 1;
  int e = xcd, z = k * 8 + e;
  int count = counts[z];
  int m0 = m * 128;
  if (m0 >= count) return;
  int n0 = n * 128;

  __shared__ _Float16 As[128 * 64];   // 16 KB
  __shared__ _Float16 Bs[256 * 64];   // 32 KB
  __shared__ int toks[128];

  int t = threadIdx.x;
  if (t < 128) {
    int r = m0 + t;
    toks[t] = (r < count) ? toklist[z * CAPP + r] : N_TOK;   // pad -> zero row
  }
  __syncthreads();

  int lane = t & 63, w = t >> 6;
  int l8 = lane >> 3, u8 = lane & 7;

  const _Float16* ag[4]; _Float16* al[4];
#pragma unroll
  for (int s = 0; s < 4; s++) {
    int row = w * 32 + s * 8 + l8;
    ag[s] = xh + (long)toks[row] * DDIM + ((u8 ^ (row & 7)) * 8);
    al[s] = As + row * 64 + u8 * 8;
  }
  const _Float16* bg[8]; _Float16* bl[8];
#pragma unroll
  for (int s = 0; s < 8; s++) {
    int rb = w * 64 + s * 8 + l8;
    int gr = (rb < 128) ? (n0 + rb) : (2048 + n0 + (rb - 128));
    bg[s] = w1t + ((long)e * 4096 + gr) * DDIM + ((u8 ^ (rb & 7)) * 8);
    bl[s] = Bs + rb * 64 + u8 * 8;
  }

  int q = lane >> 4, m16 = lane & 15;
  int wm = w & 1, wn = w >> 1;

  f4 zero4 = {0.f, 0.f, 0.f, 0.f};
  f4 acc[4][4][2];
#pragma unroll
  for (int rt = 0; rt < 4; rt++)
#pragma unroll
    for (int ct = 0; ct < 4; ct++) { acc[rt][ct][0] = zero4; acc[rt][ct][1] = zero4; }

  for (int kk = 0; kk < DDIM; kk += 64) {
    __syncthreads();
#pragma unroll
    for (int s = 0; s < 4; s++) { gld16(ag[s], al[s]); ag[s] += 64; }
#pragma unroll
    for (int s = 0; s < 8; s++) { gld16(bg[s], bl[s]); bg[s] += 64; }
    __syncthreads();

#pragma unroll
    for (int c = 0; c < 2; c++) {
      half8 af[4], bf[4][2];
#pragma unroll
      for (int rt = 0; rt < 4; rt++) {
        int row = wm * 64 + rt * 16 + m16;
        af[rt] = *(const half8*)(As + row * 64 + (((c * 4 + q) ^ (row & 7)) * 8));
      }
#pragma unroll
      for (int ct = 0; ct < 4; ct++) {
        int cb = wn * 64 + ct * 16 + m16;
        int ph = ((c * 4 + q) ^ (cb & 7)) * 8;    // (cb+128)&7 == cb&7
        bf[ct][0] = *(const half8*)(Bs + cb * 64 + ph);
        bf[ct][1] = *(const half8*)(Bs + (128 + cb) * 64 + ph);
      }
#pragma unroll
      for (int rt = 0; rt < 4; rt++)
#pragma unroll
        for (int ct = 0; ct < 4; ct++) {
          acc[rt][ct][0] = __builtin_amdgcn_mfma_f32_16x16x32_f16(af[rt], bf[ct][0], acc[rt][ct][0], 0, 0, 0);
          acc[rt][ct][1] = __builtin_amdgcn_mfma_f32_16x16x32_f16(af[rt], bf[ct][1], acc[rt][ct][1], 0, 0, 0);
        }
    }
  }

  long ab = (long)z * CAPP * HDIM;
#pragma unroll
  for (int rt = 0; rt < 4; rt++)
#pragma unroll
    for (int ct = 0; ct < 4; ct++)
#pragma unroll
      for (int r = 0; r < 4; r++) {
        int row = m0 + wm * 64 + rt * 16 + q * 4 + r;   // C/D: row = quad*4+reg
        int col = n0 + wn * 64 + ct * 16 + m16;         //      col = lane&15
        float h1 = acc[rt][ct][0][r], h2 = acc[rt][ct][1][r];
        float s = h2 / (1.f + __expf(-h2));
        act[ab + (long)row * HDIM + col] = (_Float16)(h1 * s);
      }
}

// -------------------- GEMM2 + weighted scatter (r4 structure) --------------------
__global__ __launch_bounds__(256, 3) void gemm2_kernel(const _Float16* __restrict__ act,
                                                       const _Float16* __restrict__ w2t,
                                                       const int* __restrict__ toklist,
                                                       const int* __restrict__ counts,
                                                       const float* __restrict__ wts,
                                                       float* __restrict__ out) {
  int i = blockIdx.x;
  int xcd = i & 7, j = i >> 3;       // 480 blocks, 60/xcd
  int m = j % 5, t2 = j / 5;         // t2<12: k=t2&1, n=t2>>1 (0..5)
  int k = t2 & 1, n = t2 >> 1;
  int e = xcd, z = k * 8 + e;
  int count = counts[z];
  int m0 = m * 128;
  if (m0 >= count) return;
  int n0 = n * 128;

  __shared__ _Float16 As[128 * 64];   // 16 KB
  __shared__ _Float16 Bs[128 * 64];   // 16 KB
  __shared__ int toksL[128];
  __shared__ float wrow[128];

  int t = threadIdx.x;
  if (t < 128) {
    int r = m0 + t;
    if (r < count) {
      int tok = toklist[z * CAPP + r];
      toksL[t] = tok;
      wrow[t] = wts[tok * 2 + k];
    } else {
      toksL[t] = -1;
      wrow[t] = 0.f;
    }
  }
  __syncthreads();

  int lane = t & 63, w = t >> 6;
  int l8 = lane >> 3, u8 = lane & 7;

  const _Float16* ag[4]; _Float16* al[4];
#pragma unroll
  for (int s = 0; s < 4; s++) {
    int row = w * 32 + s * 8 + l8;
    ag[s] = act + ((long)z * CAPP + m0 + row) * HDIM + ((u8 ^ (row & 7)) * 8);
    al[s] = As + row * 64 + u8 * 8;
  }
  const _Float16* bg[4]; _Float16* bl[4];
#pragma unroll
  for (int s = 0; s < 4; s++) {
    int rb = w * 32 + s * 8 + l8;
    bg[s] = w2t + ((long)e * DDIM + n0 + rb) * HDIM + ((u8 ^ (rb & 7)) * 8);
    bl[s] = Bs + rb * 64 + u8 * 8;
  }

  int q = lane >> 4, m16 = lane & 15;
  int wm = w & 1, wn = w >> 1;

  f4 zero4 = {0.f, 0.f, 0.f, 0.f};
  f4 acc[4][4];
#pragma unroll
  for (int rt = 0; rt < 4; rt++)
#pragma unroll
    for (int ct = 0; ct < 4; ct++) acc[rt][ct] = zero4;

  for (int kk = 0; kk < HDIM; kk += 64) {
    __syncthreads();
#pragma unroll
    for (int s = 0; s < 4; s++) { gld16(ag[s], al[s]); ag[s] += 64; }
#pragma unroll
    for (int s = 0; s < 4; s++) { gld16(bg[s], bl[s]); bg[s] += 64; }
    __syncthreads();

#pragma unroll
    for (int c = 0; c < 2; c++) {
      half8 af[4], bf[4];
#pragma unroll
      for (int rt = 0; rt < 4; rt++) {
        int row = wm * 64 + rt * 16 + m16;
        af[rt] = *(const half8*)(As + row * 64 + (((c * 4 + q) ^ (row & 7)) * 8));
      }
#pragma unroll
      for (int ct = 0; ct < 4; ct++) {
        int cb = wn * 64 + ct * 16 + m16;
        bf[ct] = *(const half8*)(Bs + cb * 64 + (((c * 4 + q) ^ (cb & 7)) * 8));
      }
#pragma unroll
      for (int rt = 0; rt < 4; rt++)
#pragma unroll
        for (int ct = 0; ct < 4; ct++)
          acc[rt][ct] = __builtin_amdgcn_mfma_f32_16x16x32_f16(af[rt], bf[ct], acc[rt][ct], 0, 0, 0);
    }
  }

  // weighted scatter: out[tok, col] += w * y
#pragma unroll
  for (int rt = 0; rt < 4; rt++)
#pragma unroll
    for (int ct = 0; ct < 4; ct++)
#pragma unroll
      for (int r = 0; r < 4; r++) {
        int lr = wm * 64 + rt * 16 + q * 4 + r;
        int tok = toksL[lr];
        if (tok >= 0) {
          int col = n0 + wn * 64 + ct * 16 + m16;
          atomicAdd(&out[(long)tok * DDIM + col], wrow[lr] * acc[rt][ct][r]);
        }
      }
}

// -------------------- launch --------------------

extern "C" void kernel_launch(void* const* d_in, const int* in_sizes, int n_in,
                              void* d_out, int out_size, void* d_ws, size_t ws_size,
                              hipStream_t stream) {
  const float* x  = (const float*)d_in[0];
  const float* Wg = (const float*)d_in[1];
  const float* W1 = (const float*)d_in[2];
  const float* W2 = (const float*)d_in[3];
  float* out = (float*)d_out;
  char* ws = (char*)d_ws;

  _Float16* xh   = (_Float16*)(ws + XH_OFF);
  _Float16* w1t  = (_Float16*)(ws + W1T_OFF);
  _Float16* w2t  = (_Float16*)(ws + W2T_OFF);
  _Float16* actb = (_Float16*)(ws + ACT_OFF);
  int* eidx      = (int*)(ws + EIDX_OFF);
  float* wts     = (float*)(ws + WTS_OFF);
  int* toklist   = (int*)(ws + TOKL_OFF);
  int* counts    = (int*)(ws + CNT_OFF);

  hipMemsetAsync(d_out, 0, (size_t)out_size * sizeof(float), stream);
  prep_kernel<<<10241, 256, 0, stream>>>(W1, W2, x, Wg, w1t, w2t, xh, eidx, wts);
  scan_kernel<<<16, 64, 0, stream>>>(eidx, toklist, counts);
  gemm1_kernel<<<1280, 256, 0, stream>>>(xh, w1t, toklist, counts, actb);
  gemm2_kernel<<<480, 256, 0, stream>>>(actb, w2t, toklist, counts, wts, out);
}

// Round 5
// 332.046 us; speedup vs baseline: 1.1123x; 1.0296x over previous
//
#include <hip/hip_runtime.h>

// GatedMoE on MI355X (gfx950), fp16 MFMA path, round 9.
// vs r8: prep was top dispatch (83.8us, all pipes idle -> latency-bound).
// (a) cvt blocks widened to 64x128 (2 tiles per block, 8 f4 loads in
// flight before one barrier) for 2x MLP and half the per-byte overhead;
// (b) cvt(W2) blocks appended to gemm1's launch (gemm1 never reads w2t;
// gemm2 starts only after the full grid drains) so W2 conversion rides
// gemm1's idle memory pipe. GEMM structure = verified r4 (3 blocks/CU).

typedef _Float16 half8 __attribute__((ext_vector_type(8)));
typedef _Float16 half4t __attribute__((ext_vector_type(4)));
typedef float f4 __attribute__((ext_vector_type(4)));

#define N_TOK 4096
#define DDIM  768
#define HDIM  2048
#define NEXP  8
#define CAP   614   // int(1.2 * 4096 / 8)
#define CAPP  640

// ---- workspace layout (bytes) ----
#define XH_OFF    0L           // (4097*768) fp16
#define W1T_OFF   6292992L     // [8][4096][768] fp16
#define W2T_OFF   56624640L    // [8][768][2048] fp16
#define ACT_OFF   81790464L    // [16][640][2048] fp16
#define EIDX_OFF  123733504L   // [4096][2] int
#define WTS_OFF   123766272L   // [4096][2] float
#define TOKL_OFF  123799040L   // [16][640] int
#define CNT_OFF   123840000L   // [16] int

__device__ __forceinline__ void gld16(const void* g, void* l) {
  __builtin_amdgcn_global_load_lds(
      (const __attribute__((address_space(1))) unsigned int*)g,
      (__attribute__((address_space(3))) unsigned int*)l, 16, 0, 0);
}

// -------------------- wide transpose+convert: 64 rows x 128 cols --------------------
// src fp32 [e][R][C] tile at (r0, c0) -> dst fp16 [e][C][R].
// 8 f4 loads per thread in flight before the single barrier (2x MLP vs r8).
__device__ __forceinline__ void cvt2_tile(const float* __restrict__ src,
                                          _Float16* __restrict__ dst,
                                          int R, int C, int e, int r0, int c0,
                                          float* __restrict__ tile) {
  long sb = (long)e * R * C;
  int t = threadIdx.x;
  int rrow = t >> 4, c4 = (t & 15) * 4;
#pragma unroll
  for (int h = 0; h < 2; h++)
#pragma unroll
    for (int i = 0; i < 4; i++) {
      int row = i * 16 + rrow;
      f4 v = *(const f4*)(src + sb + (long)(r0 + row) * C + c0 + h * 64 + c4);
      *(f4*)(&tile[h * 4416 + row * 69 + c4]) = v;
    }
  __syncthreads();
#pragma unroll
  for (int h = 0; h < 2; h++)
#pragma unroll
    for (int s = 0; s < 2; s++) {
      int idx = t + s * 256;
      int c = idx >> 3, ch = idx & 7;
      half8 hv;
#pragma unroll
      for (int j = 0; j < 8; j++) hv[j] = (_Float16)tile[h * 4416 + (ch * 8 + j) * 69 + c];
      *(half8*)(dst + sb + (long)(c0 + h * 64 + c) * R + r0 + ch * 8) = hv;
    }
}

// -------------------- prep1: cvt_tr(W1) | router --------------------
// blocks [0,3072): W1 [8][768][4096] fp32 -> w1t [8][4096][768] fp16 (64x128 tiles)
// blocks [3072,4097): router + x->fp16 convert (4 tokens/block)
__global__ __launch_bounds__(256) void prep1_kernel(const float* __restrict__ W1,
                                                    const float* __restrict__ x,
                                                    const float* __restrict__ Wg,
                                                    _Float16* __restrict__ w1t,
                                                    _Float16* __restrict__ xh,
                                                    int* __restrict__ eidx,
                                                    float* __restrict__ wts) {
  __shared__ float smem[2 * 4416];   // 35.3 KB: cvt tiles or wgT (24 KB)
  int b = blockIdx.x;

  if (b < 3072) {                    // ---- cvt W1
    int e = b / 384, rem = b % 384;
    int cx = rem % 12, cy = rem / 12;       // 12 r-tiles x 32 col2-tiles
    cvt2_tile(W1, w1t, 768, 4096, e, cx * 64, cy * 128, smem);
    return;
  }

  // ---- router (block-uniform path)
  int rb = b - 3072;                 // 0..1024
  int t = threadIdx.x;
  for (int i = t; i < DDIM * NEXP; i += 256) smem[(i & 7) * DDIM + (i >> 3)] = Wg[i];
  __syncthreads();
  int w = t >> 6, lane = t & 63;
  int tok = rb * 4 + w;
  if (tok > N_TOK) return;
  if (tok == N_TOK) {                // zero pad row
    half4t zz; zz[0] = zz[1] = zz[2] = zz[3] = (_Float16)0.f;
#pragma unroll
    for (int j = 0; j < 3; j++) *(half4t*)(xh + (long)N_TOK * DDIM + (lane + j * 64) * 4) = zz;
    return;
  }
  const float* xr = x + (long)tok * DDIM;
#pragma unroll
  for (int j = 0; j < 3; j++) {
    f4 v = *(const f4*)(xr + (lane + j * 64) * 4);
    half4t hv;
    hv[0] = (_Float16)v[0]; hv[1] = (_Float16)v[1];
    hv[2] = (_Float16)v[2]; hv[3] = (_Float16)v[3];
    *(half4t*)(xh + (long)tok * DDIM + (lane + j * 64) * 4) = hv;
  }
  float acc[8] = {0.f, 0.f, 0.f, 0.f, 0.f, 0.f, 0.f, 0.f};
#pragma unroll
  for (int i = 0; i < 12; i++) {
    float xv = xr[i * 64 + lane];
#pragma unroll
    for (int e2 = 0; e2 < 8; e2++) acc[e2] += xv * smem[e2 * DDIM + i * 64 + lane];
  }
#pragma unroll
  for (int e2 = 0; e2 < 8; e2++) {
    float v = acc[e2];
    v += __shfl_xor(v, 32); v += __shfl_xor(v, 16); v += __shfl_xor(v, 8);
    v += __shfl_xor(v, 4);  v += __shfl_xor(v, 2);  v += __shfl_xor(v, 1);
    acc[e2] = v;
  }
  if (lane == 0) {
    float m0 = -1e30f; int i0 = 0;
#pragma unroll
    for (int e2 = 0; e2 < 8; e2++) if (acc[e2] > m0) { m0 = acc[e2]; i0 = e2; }
    float m1 = -1e30f; int i1 = 0;
#pragma unroll
    for (int e2 = 0; e2 < 8; e2++) if (e2 != i0 && acc[e2] > m1) { m1 = acc[e2]; i1 = e2; }
    float tt = __expf(m1 - m0);
    float w0 = 1.f / (1.f + tt);
    eidx[tok * 2 + 0] = i0; eidx[tok * 2 + 1] = i1;
    wts[tok * 2 + 0] = w0;  wts[tok * 2 + 1] = 1.f - w0;
  }
}

// -------------------- capacity scan (16 blocks, one per (k,e)) --------------------
__global__ __launch_bounds__(64) void scan_kernel(const int* __restrict__ eidx,
                                                  int* __restrict__ toklist,
                                                  int* __restrict__ counts) {
  int z = blockIdx.x;
  int k = z >> 3, e = z & 7;
  int lane = threadIdx.x;
  int mye[64];
#pragma unroll
  for (int c = 0; c < 64; c++) mye[c] = eidx[(c * 64 + lane) * 2 + k];
  int base = 0;
#pragma unroll 4
  for (int c = 0; c < 64; c++) {
    int n = c * 64 + lane;
    bool pred = (mye[c] == e);
    unsigned long long mask = __ballot(pred);
    if (pred) {
      int pos = base + __popcll(mask & ((1ull << lane) - 1ull));
      if (pos < CAP) toklist[z * CAPP + pos] = n;
    }
    base += __popcll(mask);
  }
  if (lane == 0) counts[z] = (base < CAP) ? base : CAP;
}

// -------------------- GEMM1 + fused SwiGLU | cvt_tr(W2) --------------------
// blocks [0,1280): gemm1 (r4 structure, 128x128 act-col tile, BK=64)
// blocks [1280,2816): W2 [8][2048][768] fp32 -> w2t [8][768][2048] fp16
//   (rides gemm1's idle memory pipe; gemm2 waits for the whole grid)
__global__ __launch_bounds__(256, 2) void gemm1_kernel(const _Float16* __restrict__ xh,
                                                       const _Float16* __restrict__ w1t,
                                                       const float* __restrict__ W2,
                                                       _Float16* __restrict__ w2t,
                                                       const int* __restrict__ toklist,
                                                       const int* __restrict__ counts,
                                                       _Float16* __restrict__ act) {
  __shared__ char smem[49664];   // gemm1: As 16K | Bs 32K | toks 512. cvt: 35.3K

  int i = blockIdx.x;
  if (i >= 1280) {                   // ---- cvt W2 path
    int b2 = i - 1280;               // 0..1535
    int e = b2 / 192, rem = b2 % 192;
    int cx = rem % 32, cy = rem / 32;      // 32 r-tiles x 6 col2-tiles
    cvt2_tile(W2, w2t, 2048, 768, e, cx * 64, cy * 128, (float*)smem);
    return;
  }

  _Float16* As = (_Float16*)smem;             // 128*64
  _Float16* Bs = (_Float16*)(smem + 16384);   // 256*64
  int* toks = (int*)(smem + 49152);           // 128

  int xcd = i & 7, j = i >> 3;       // 1280 blocks, 160/xcd
  int m = j % 5, ii = j / 5;
  int k = ii & 1, n = ii >> 1;
  int e = xcd, z = k * 8 + e;
  int count = counts[z];
  int m0 = m * 128;
  if (m0 >= count) return;
  int n0 = n * 128;

  int t = threadIdx.x;
  if (t < 128) {
    int r = m0 + t;
    toks[t] = (r < count) ? toklist[z * CAPP + r] : N_TOK;   // pad -> zero row
  }
  __syncthreads();

  int lane = t & 63, w = t >> 6;
  int l8 = lane >> 3, u8 = lane & 7;

  const _Float16* ag[4]; _Float16* al[4];
#pragma unroll
  for (int s = 0; s < 4; s++) {
    int row = w * 32 + s * 8 + l8;
    ag[s] = xh + (long)toks[row] * DDIM + ((u8 ^ (row & 7)) * 8);
    al[s] = As + row * 64 + u8 * 8;
  }
  const _Float16* bg[8]; _Float16* bl[8];
#pragma unroll
  for (int s = 0; s < 8; s++) {
    int rb = w * 64 + s * 8 + l8;
    int gr = (rb < 128) ? (n0 + rb) : (2048 + n0 + (rb - 128));
    bg[s] = w1t + ((long)e * 4096 + gr) * DDIM + ((u8 ^ (rb & 7)) * 8);
    bl[s] = Bs + rb * 64 + u8 * 8;
  }

  int q = lane >> 4, m16 = lane & 15;
  int wm = w & 1, wn = w >> 1;

  f4 zero4 = {0.f, 0.f, 0.f, 0.f};
  f4 acc[4][4][2];
#pragma unroll
  for (int rt = 0; rt < 4; rt++)
#pragma unroll
    for (int ct = 0; ct < 4; ct++) { acc[rt][ct][0] = zero4; acc[rt][ct][1] = zero4; }

  for (int kk = 0; kk < DDIM; kk += 64) {
    __syncthreads();
#pragma unroll
    for (int s = 0; s < 4; s++) { gld16(ag[s], al[s]); ag[s] += 64; }
#pragma unroll
    for (int s = 0; s < 8; s++) { gld16(bg[s], bl[s]); bg[s] += 64; }
    __syncthreads();

#pragma unroll
    for (int c = 0; c < 2; c++) {
      half8 af[4], bf[4][2];
#pragma unroll
      for (int rt = 0; rt < 4; rt++) {
        int row = wm * 64 + rt * 16 + m16;
        af[rt] = *(const half8*)(As + row * 64 + (((c * 4 + q) ^ (row & 7)) * 8));
      }
#pragma unroll
      for (int ct = 0; ct < 4; ct++) {
        int cb = wn * 64 + ct * 16 + m16;
        int ph = ((c * 4 + q) ^ (cb & 7)) * 8;    // (cb+128)&7 == cb&7
        bf[ct][0] = *(const half8*)(Bs + cb * 64 + ph);
        bf[ct][1] = *(const half8*)(Bs + (128 + cb) * 64 + ph);
      }
#pragma unroll
      for (int rt = 0; rt < 4; rt++)
#pragma unroll
        for (int ct = 0; ct < 4; ct++) {
          acc[rt][ct][0] = __builtin_amdgcn_mfma_f32_16x16x32_f16(af[rt], bf[ct][0], acc[rt][ct][0], 0, 0, 0);
          acc[rt][ct][1] = __builtin_amdgcn_mfma_f32_16x16x32_f16(af[rt], bf[ct][1], acc[rt][ct][1], 0, 0, 0);
        }
    }
  }

  long ab = (long)z * CAPP * HDIM;
#pragma unroll
  for (int rt = 0; rt < 4; rt++)
#pragma unroll
    for (int ct = 0; ct < 4; ct++)
#pragma unroll
      for (int r = 0; r < 4; r++) {
        int row = m0 + wm * 64 + rt * 16 + q * 4 + r;   // C/D: row = quad*4+reg
        int col = n0 + wn * 64 + ct * 16 + m16;         //      col = lane&15
        float h1 = acc[rt][ct][0][r], h2 = acc[rt][ct][1][r];
        float s = h2 / (1.f + __expf(-h2));
        act[ab + (long)row * HDIM + col] = (_Float16)(h1 * s);
      }
}

// -------------------- GEMM2 + weighted scatter (r4 structure) --------------------
__global__ __launch_bounds__(256, 3) void gemm2_kernel(const _Float16* __restrict__ act,
                                                       const _Float16* __restrict__ w2t,
                                                       const int* __restrict__ toklist,
                                                       const int* __restrict__ counts,
                                                       const float* __restrict__ wts,
                                                       float* __restrict__ out) {
  int i = blockIdx.x;
  int xcd = i & 7, j = i >> 3;       // 480 blocks, 60/xcd
  int m = j % 5, t2 = j / 5;         // t2<12: k=t2&1, n=t2>>1 (0..5)
  int k = t2 & 1, n = t2 >> 1;
  int e = xcd, z = k * 8 + e;
  int count = counts[z];
  int m0 = m * 128;
  if (m0 >= count) return;
  int n0 = n * 128;

  __shared__ _Float16 As[128 * 64];   // 16 KB
  __shared__ _Float16 Bs[128 * 64];   // 16 KB
  __shared__ int toksL[128];
  __shared__ float wrow[128];

  int t = threadIdx.x;
  if (t < 128) {
    int r = m0 + t;
    if (r < count) {
      int tok = toklist[z * CAPP + r];
      toksL[t] = tok;
      wrow[t] = wts[tok * 2 + k];
    } else {
      toksL[t] = -1;
      wrow[t] = 0.f;
    }
  }
  __syncthreads();

  int lane = t & 63, w = t >> 6;
  int l8 = lane >> 3, u8 = lane & 7;

  const _Float16* ag[4]; _Float16* al[4];
#pragma unroll
  for (int s = 0; s < 4; s++) {
    int row = w * 32 + s * 8 + l8;
    ag[s] = act + ((long)z * CAPP + m0 + row) * HDIM + ((u8 ^ (row & 7)) * 8);
    al[s] = As + row * 64 + u8 * 8;
  }
  const _Float16* bg[4]; _Float16* bl[4];
#pragma unroll
  for (int s = 0; s < 4; s++) {
    int rb = w * 32 + s * 8 + l8;
    bg[s] = w2t + ((long)e * DDIM + n0 + rb) * HDIM + ((u8 ^ (rb & 7)) * 8);
    bl[s] = Bs + rb * 64 + u8 * 8;
  }

  int q = lane >> 4, m16 = lane & 15;
  int wm = w & 1, wn = w >> 1;

  f4 zero4 = {0.f, 0.f, 0.f, 0.f};
  f4 acc[4][4];
#pragma unroll
  for (int rt = 0; rt < 4; rt++)
#pragma unroll
    for (int ct = 0; ct < 4; ct++) acc[rt][ct] = zero4;

  for (int kk = 0; kk < HDIM; kk += 64) {
    __syncthreads();
#pragma unroll
    for (int s = 0; s < 4; s++) { gld16(ag[s], al[s]); ag[s] += 64; }
#pragma unroll
    for (int s = 0; s < 4; s++) { gld16(bg[s], bl[s]); bg[s] += 64; }
    __syncthreads();

#pragma unroll
    for (int c = 0; c < 2; c++) {
      half8 af[4], bf[4];
#pragma unroll
      for (int rt = 0; rt < 4; rt++) {
        int row = wm * 64 + rt * 16 + m16;
        af[rt] = *(const half8*)(As + row * 64 + (((c * 4 + q) ^ (row & 7)) * 8));
      }
#pragma unroll
      for (int ct = 0; ct < 4; ct++) {
        int cb = wn * 64 + ct * 16 + m16;
        bf[ct] = *(const half8*)(Bs + cb * 64 + (((c * 4 + q) ^ (cb & 7)) * 8));
      }
#pragma unroll
      for (int rt = 0; rt < 4; rt++)
#pragma unroll
        for (int ct = 0; ct < 4; ct++)
          acc[rt][ct] = __builtin_amdgcn_mfma_f32_16x16x32_f16(af[rt], bf[ct], acc[rt][ct], 0, 0, 0);
    }
  }

  // weighted scatter: out[tok, col] += w * y
#pragma unroll
  for (int rt = 0; rt < 4; rt++)
#pragma unroll
    for (int ct = 0; ct < 4; ct++)
#pragma unroll
      for (int r = 0; r < 4; r++) {
        int lr = wm * 64 + rt * 16 + q * 4 + r;
        int tok = toksL[lr];
        if (tok >= 0) {
          int col = n0 + wn * 64 + ct * 16 + m16;
          atomicAdd(&out[(long)tok * DDIM + col], wrow[lr] * acc[rt][ct][r]);
        }
      }
}

// -------------------- launch --------------------

extern "C" void kernel_launch(void* const* d_in, const int* in_sizes, int n_in,
                              void* d_out, int out_size, void* d_ws, size_t ws_size,
                              hipStream_t stream) {
  const float* x  = (const float*)d_in[0];
  const float* Wg = (const float*)d_in[1];
  const float* W1 = (const float*)d_in[2];
  const float* W2 = (const float*)d_in[3];
  float* out = (float*)d_out;
  char* ws = (char*)d_ws;

  _Float16* xh   = (_Float16*)(ws + XH_OFF);
  _Float16* w1t  = (_Float16*)(ws + W1T_OFF);
  _Float16* w2t  = (_Float16*)(ws + W2T_OFF);
  _Float16* actb = (_Float16*)(ws + ACT_OFF);
  int* eidx      = (int*)(ws + EIDX_OFF);
  float* wts     = (float*)(ws + WTS_OFF);
  int* toklist   = (int*)(ws + TOKL_OFF);
  int* counts    = (int*)(ws + CNT_OFF);

  hipMemsetAsync(d_out, 0, (size_t)out_size * sizeof(float), stream);
  prep1_kernel<<<4097, 256, 0, stream>>>(W1, x, Wg, w1t, xh, eidx, wts);
  scan_kernel<<<16, 64, 0, stream>>>(eidx, toklist, counts);
  gemm1_kernel<<<2816, 256, 0, stream>>>(xh, w1t, W2, w2t, toklist, counts, actb);
  gemm2_kernel<<<480, 256, 0, stream>>>(actb, w2t, toklist, counts, wts, out);
}